// Round 10
// baseline (51.485 us; speedup 1.0000x reference)
//
#include <hip/hip_runtime.h>
#include <math.h>

#define BB 4
#define NN 16384
#define CC 128
#define MM 128
#define SS 512
#define OUT_ROW 131                    // 3 coords + 128 features
#define NSEG 256                       // 16384 / 64 segments per box
#define ELEMS_PER_BOX (SS * OUT_ROW)   // 67072
#define NQBLK (BB * MM * 4)            // 2048 persistent blocks, 128 rows each

typedef float f32x4 __attribute__((ext_vector_type(4)));

// ---------------- K1: per-box stable in-box index selection ----------------
// 512 blocks (one per box) x 512 threads (8 waves).
// Emits ws_idx[bm][0..SS) with the row%cnt wrap ALREADY applied.
__global__ __launch_bounds__(512) void k1_select(
    const float* __restrict__ points,   // (B, N, 3)
    const float* __restrict__ boxes,    // (B, M, 7)
    int* __restrict__ ws_idx,           // (B*M, SS)
    int* __restrict__ ws_cnt,           // (B*M)
    float* __restrict__ out_flag)       // (B*M) as float 0/1
{
    const int bm   = blockIdx.x;
    const int b    = bm >> 7;
    const int m    = bm & (MM - 1);
    const int tid  = threadIdx.x;
    const int lane = tid & 63;
    const int wave = tid >> 6;

    __shared__ unsigned long long s_mask[NSEG];
    __shared__ int s_wsum[4];

    // box params, enlarged: cz -= 0.5, d* += 1.0
    const float* bx = boxes + (size_t)(b * MM + m) * 7;
    const float cx  = bx[0];
    const float cy  = bx[1];
    const float cz  = __fadd_rn(bx[2], -0.5f);
    const float hx  = __fmul_rn(__fadd_rn(bx[3], 1.0f), 0.5f);
    const float hy  = __fmul_rn(__fadd_rn(bx[4], 1.0f), 0.5f);
    const float hz  = __fmul_rn(__fadd_rn(bx[5], 1.0f), 0.5f);
    const float yaw = bx[6];
    const float cosa = (float)cos((double)yaw);
    const float sina = (float)sin((double)yaw);
    const float zc   = __fadd_rn(cz, hz);

    const float* pbase = points + (size_t)b * NN * 3;

    // ---- Pass A: wave w handles segments [w*32, w*32+32) ----
    #pragma unroll 4
    for (int k = 0; k < 32; ++k) {
        const int s = wave * 32 + k;
        const int i = s * 64 + lane;
        const float px = pbase[i * 3 + 0];
        const float py = pbase[i * 3 + 1];
        const float pz = pbase[i * 3 + 2];
        const float sx = __fadd_rn(px, -cx);
        const float sy = __fadd_rn(py, -cy);
        const float lx = __fadd_rn(__fmul_rn(sx, cosa), __fmul_rn(sy, sina));
        const float ly = __fadd_rn(__fmul_rn(-sx, sina), __fmul_rn(sy, cosa));
        const bool in_box = (fabsf(lx) < hx) & (fabsf(ly) < hy) &
                            (fabsf(__fadd_rn(pz, -zc)) <= hz);
        const unsigned long long mask = __ballot(in_box);
        if (lane == 0) s_mask[s] = mask;
    }
    __syncthreads();

    // ---- Pass B: prefix scan over 256 segment counts (threads 0..255) ----
    unsigned long long mymask = 0ull;
    int c = 0;
    if (tid < NSEG) {
        mymask = s_mask[tid];
        c = __popcll(mymask);
    }
    int inc = c;
    #pragma unroll
    for (int d = 1; d < 64; d <<= 1) {
        int v = __shfl_up(inc, d);
        if (lane >= d) inc += v;
    }
    if (tid < NSEG && lane == 63) s_wsum[wave] = inc;
    __syncthreads();

    int woff = 0, total = 0;
    #pragma unroll
    for (int w = 0; w < 4; ++w) {
        const int v = s_wsum[w];
        if (w < wave) woff += v;
        total += v;
    }

    int* dst = ws_idx + (size_t)bm * SS;

    // ---- Pass C: emit indices (stable ascending order), first SS only ----
    if (tid < NSEG) {
        int base = woff + inc - c;          // exclusive prefix
        if (base < SS) {
            unsigned long long mk = mymask;
            while (mk) {
                const int bit = __ffsll(mk) - 1;
                mk &= mk - 1;
                dst[base] = tid * 64 + bit;
                if (++base >= SS) break;
            }
        }
    }
    __syncthreads();

    // ---- Pass D: expand with row % cnt wrap so K2 needs no division ----
    const int cnt = total;
    if (cnt > 0) {
        for (int row = cnt + tid; row < SS; row += 512)
            dst[row] = dst[row % cnt];
    }
    if (tid == 0) {
        ws_cnt[bm] = cnt;
        out_flag[bm] = (cnt == 0) ? 1.0f : 0.0f;
    }
}

// ---------------- K2: software-pipelined persistent gather ----------------
// 2048 blocks x 256 threads (8 blocks/CU = 100% occ). Block owns 128 rows of
// one box; wave owns 32 rows = 4 sub-tiles of 8 rows, double-buffered:
// sub-tile t+1's gathers are issued BEFORE sub-tile t's LDS-bounce + NT store,
// so gather latency hides under the store phase (async-stage split, G15).
// No barriers: per-wave LDS slice + in-order DS ops. Bijective XCD swizzle.
__global__ __launch_bounds__(256) void k2_gather(
    const float* __restrict__ points,
    const float* __restrict__ feats,    // (B, N, C)
    const int* __restrict__ ws_idx,
    const int* __restrict__ ws_cnt,
    float* __restrict__ out_feat)       // (B, M, S, 131)
{
    const int orig = blockIdx.x;
    const int blk  = ((orig & 7) << 8) | (orig >> 3);   // 2048 = 8 XCD x 256
    const int bm   = blk >> 2;
    const int q    = blk & 3;
    const int lane = threadIdx.x & 63;
    const int wave = threadIdx.x >> 6;

    const int cnt = ws_cnt[bm];
    const int rowbase = q * 128 + wave * 32;            // wave's 32 rows in box
    float* owave = out_feat + (size_t)bm * ELEMS_PER_BOX
                 + (size_t)rowbase * OUT_ROW;           // 1048 f32x4, 16B-aligned

    if (cnt == 0) {
        const f32x4 z = (f32x4)0.0f;
        #pragma unroll
        for (int it = 0; it < 16; ++it)
            __builtin_nontemporal_store(z, (f32x4*)owave + it * 64 + lane);
        if (lane < 24)
            __builtin_nontemporal_store(z, (f32x4*)owave + 1024 + lane);
        return;
    }

    __shared__ float s_tile[4 * 8 * OUT_ROW];  // per-wave 8-row slice (4192 B)
    float* wtile = s_tile + wave * (8 * OUT_ROW);

    const int b = bm >> 7;
    const float* pb = points + (size_t)b * NN * 3;
    const float* fb = feats + (size_t)b * NN * CC;
    const int half = lane >> 5;
    const int sl   = lane & 31;
    const int cr   = (lane < 24) ? lane / 3 : 0;        // coord row 0..7
    const int cc   = lane - (lane / 3) * 3;
    const int* idx = ws_idx + (size_t)bm * SS + rowbase;
    const int idxreg = idx[lane & 31];  // lanes hold this wave's 32 row indices

    f32x4 vA[4], vB[4];
    float cvA, cvB;

    // prologue: issue sub-tile 0's gathers + coord load
    #pragma unroll
    for (int p = 0; p < 4; ++p) {
        const int pi = __shfl(idxreg, p * 2 + half);
        vA[p] = *(const f32x4*)(fb + (size_t)pi * CC + sl * 4);
    }
    {
        const int cpi = __shfl(idxreg, cr);
        cvA = (lane < 24) ? pb[cpi * 3 + cc] : 0.0f;
    }

    #pragma unroll
    for (int t = 0; t < 4; ++t) {
        f32x4* cur = (t & 1) ? vB : vA;
        f32x4* nxt = (t & 1) ? vA : vB;
        float  ccur = (t & 1) ? cvB : cvA;

        // issue next sub-tile's loads first (stay in flight through the store)
        if (t < 3) {
            #pragma unroll
            for (int p = 0; p < 4; ++p) {
                const int pi = __shfl(idxreg, (t + 1) * 8 + p * 2 + half);
                nxt[p] = *(const f32x4*)(fb + (size_t)pi * CC + sl * 4);
            }
            const int cpi = __shfl(idxreg, (t + 1) * 8 + cr);
            const float cv = (lane < 24) ? pb[cpi * 3 + cc] : 0.0f;
            if (t & 1) cvA = cv; else cvB = cv;
        }

        // LDS-bounce current sub-tile
        #pragma unroll
        for (int p = 0; p < 4; ++p) {
            float* d = wtile + (p * 2 + half) * OUT_ROW + 3 + sl * 4;
            d[0] = cur[p].x; d[1] = cur[p].y; d[2] = cur[p].z; d[3] = cur[p].w;
        }
        if (lane < 24) wtile[cr * OUT_ROW + cc] = ccur;

        // stream the 8-row slice out: 262 aligned NT dwordx4
        float* osub = owave + (size_t)(t * 8) * OUT_ROW;
        #pragma unroll
        for (int it = 0; it < 4; ++it) {
            const int e4 = it * 64 + lane;
            const int e  = e4 * 4;
            f32x4 v;
            v.x = wtile[e + 0]; v.y = wtile[e + 1];
            v.z = wtile[e + 2]; v.w = wtile[e + 3];
            __builtin_nontemporal_store(v, (f32x4*)osub + e4);
        }
        if (lane < 6) {
            const int e4 = 256 + lane;
            const int e  = e4 * 4;
            f32x4 v;
            v.x = wtile[e + 0]; v.y = wtile[e + 1];
            v.z = wtile[e + 2]; v.w = wtile[e + 3];
            __builtin_nontemporal_store(v, (f32x4*)osub + e4);
        }
    }
}

extern "C" void kernel_launch(void* const* d_in, const int* in_sizes, int n_in,
                              void* d_out, int out_size, void* d_ws, size_t ws_size,
                              hipStream_t stream) {
    const float* points = (const float*)d_in[0];
    const float* feats  = (const float*)d_in[1];
    const float* boxes  = (const float*)d_in[2];
    float* out_feat = (float*)d_out;
    float* out_flag = (float*)d_out + (size_t)BB * MM * SS * OUT_ROW;

    int* ws_idx = (int*)d_ws;                       // 512*512 ints = 1 MB
    int* ws_cnt = ws_idx + (size_t)BB * MM * SS;    // 512 ints

    k1_select<<<BB * MM, 512, 0, stream>>>(points, boxes, ws_idx, ws_cnt, out_flag);
    k2_gather<<<NQBLK, 256, 0, stream>>>(points, feats, ws_idx, ws_cnt, out_feat);
}

// Round 11
// 49.205 us; speedup vs baseline: 1.0463x; 1.0463x over previous
//
#include <hip/hip_runtime.h>
#include <math.h>

#define BB 4
#define NN 16384
#define CC 128
#define MM 128
#define SS 512
#define OUT_ROW 131                    // 3 coords + 128 features
#define NSEG 256                       // 16384 / 64 segments per box
#define ELEMS_PER_BOX (SS * OUT_ROW)   // 67072
#define G2 16                          // row-groups per box (32 rows each)
#define QPB 1048                       // quads per block (32*131/4)

typedef float f32x4 __attribute__((ext_vector_type(4)));

// ---------------- K1: per-box stable in-box index selection ----------------
// 512 blocks (one per box) x 512 threads (8 waves).
// Emits ws_idx[bm][0..SS) with the row%cnt wrap ALREADY applied.
__global__ __launch_bounds__(512) void k1_select(
    const float* __restrict__ points,   // (B, N, 3)
    const float* __restrict__ boxes,    // (B, M, 7)
    int* __restrict__ ws_idx,           // (B*M, SS)
    int* __restrict__ ws_cnt,           // (B*M)
    float* __restrict__ out_flag)       // (B*M) as float 0/1
{
    const int bm   = blockIdx.x;
    const int b    = bm >> 7;
    const int m    = bm & (MM - 1);
    const int tid  = threadIdx.x;
    const int lane = tid & 63;
    const int wave = tid >> 6;

    __shared__ unsigned long long s_mask[NSEG];
    __shared__ int s_wsum[4];

    // box params, enlarged: cz -= 0.5, d* += 1.0
    const float* bx = boxes + (size_t)(b * MM + m) * 7;
    const float cx  = bx[0];
    const float cy  = bx[1];
    const float cz  = __fadd_rn(bx[2], -0.5f);
    const float hx  = __fmul_rn(__fadd_rn(bx[3], 1.0f), 0.5f);
    const float hy  = __fmul_rn(__fadd_rn(bx[4], 1.0f), 0.5f);
    const float hz  = __fmul_rn(__fadd_rn(bx[5], 1.0f), 0.5f);
    const float yaw = bx[6];
    const float cosa = (float)cos((double)yaw);
    const float sina = (float)sin((double)yaw);
    const float zc   = __fadd_rn(cz, hz);

    const float* pbase = points + (size_t)b * NN * 3;

    // ---- Pass A: wave w handles segments [w*32, w*32+32) ----
    #pragma unroll 4
    for (int k = 0; k < 32; ++k) {
        const int s = wave * 32 + k;
        const int i = s * 64 + lane;
        const float px = pbase[i * 3 + 0];
        const float py = pbase[i * 3 + 1];
        const float pz = pbase[i * 3 + 2];
        const float sx = __fadd_rn(px, -cx);
        const float sy = __fadd_rn(py, -cy);
        const float lx = __fadd_rn(__fmul_rn(sx, cosa), __fmul_rn(sy, sina));
        const float ly = __fadd_rn(__fmul_rn(-sx, sina), __fmul_rn(sy, cosa));
        const bool in_box = (fabsf(lx) < hx) & (fabsf(ly) < hy) &
                            (fabsf(__fadd_rn(pz, -zc)) <= hz);
        const unsigned long long mask = __ballot(in_box);
        if (lane == 0) s_mask[s] = mask;
    }
    __syncthreads();

    // ---- Pass B: prefix scan over 256 segment counts (threads 0..255) ----
    unsigned long long mymask = 0ull;
    int c = 0;
    if (tid < NSEG) {
        mymask = s_mask[tid];
        c = __popcll(mymask);
    }
    int inc = c;
    #pragma unroll
    for (int d = 1; d < 64; d <<= 1) {
        int v = __shfl_up(inc, d);
        if (lane >= d) inc += v;
    }
    if (tid < NSEG && lane == 63) s_wsum[wave] = inc;
    __syncthreads();

    int woff = 0, total = 0;
    #pragma unroll
    for (int w = 0; w < 4; ++w) {
        const int v = s_wsum[w];
        if (w < wave) woff += v;
        total += v;
    }

    int* dst = ws_idx + (size_t)bm * SS;

    // ---- Pass C: emit indices (stable ascending order), first SS only ----
    if (tid < NSEG) {
        int base = woff + inc - c;          // exclusive prefix
        if (base < SS) {
            unsigned long long mk = mymask;
            while (mk) {
                const int bit = __ffsll(mk) - 1;
                mk &= mk - 1;
                dst[base] = tid * 64 + bit;
                if (++base >= SS) break;
            }
        }
    }
    __syncthreads();

    // ---- Pass D: expand with row % cnt wrap so K2 needs no division ----
    const int cnt = total;
    if (cnt > 0) {
        for (int row = cnt + tid; row < SS; row += 512)
            dst[row] = dst[row % cnt];
    }
    if (tid == 0) {
        ws_cnt[bm] = cnt;
        out_flag[bm] = (cnt == 0) ? 1.0f : 0.0f;
    }
}

// ---------------- K2: direct gather -> NT store (no LDS data bounce) ----------------
// 8192 blocks (box x 16 groups of 32 rows) x 256 threads. Per output quad:
// fast path (col in [3,127], 95.4%) = one 4B-aligned f32x4 feature load +
// one aligned NT dwordx4 store. Special quads (coords / row-crossing) take a
// 4-scalar exec-masked path. Two-phase (all loads, then all stores) for MLP.
// Bijective XCD swizzle: 64 consecutive boxes per XCD.
__global__ __launch_bounds__(256) void k2_gather(
    const float* __restrict__ points,
    const float* __restrict__ feats,    // (B, N, C)
    const int* __restrict__ ws_idx,
    const int* __restrict__ ws_cnt,
    float* __restrict__ out_feat)       // (B, M, S, 131)
{
    const int orig = blockIdx.x;
    const int blk  = ((orig & 7) << 10) | (orig >> 3);   // 8192 = 8 XCD x 1024
    const int bm   = blk >> 4;
    const int g    = blk & (G2 - 1);
    const int row0 = g << 5;
    const int tid  = threadIdx.x;

    const int cnt = ws_cnt[bm];
    // block's output region: 32 rows = 1048 quads, 16B-aligned (4192 % 4 == 0)
    f32x4* oq = (f32x4*)(out_feat + (size_t)bm * ELEMS_PER_BOX
                                  + (size_t)row0 * OUT_ROW);

    if (cnt == 0) {
        const f32x4 z = (f32x4)0.0f;
        #pragma unroll
        for (int it = 0; it < 5; ++it) {
            const int e4 = tid + it * 256;
            if (it == 4 && tid >= QPB - 1024) continue;
            __builtin_nontemporal_store(z, oq + e4);
        }
        return;
    }

    __shared__ int s_pi[33];            // 32 rows + 1 for row-crossing quads
    if (tid < 33) {
        int r = row0 + tid; if (r > SS - 1) r = SS - 1;  // clamp (never used)
        s_pi[tid] = ws_idx[(size_t)bm * SS + r];
    }
    __syncthreads();

    const int b = bm >> 7;
    const float* pb = points + (size_t)b * NN * 3;
    const float* fb = feats + (size_t)b * NN * CC;

    f32x4 vv[5];
    // phase 1: gather all quads into registers (independent loads in flight)
    #pragma unroll
    for (int it = 0; it < 5; ++it) {
        const int e4 = tid + it * 256;
        if (it == 4 && tid >= QPB - 1024) continue;
        const int e   = e4 * 4;
        const int rl  = e / 131;                 // magic-mul const div
        const int col = e - rl * 131;
        if (col >= 3 && col <= 127) {
            const int pi = s_pi[rl];
            f32x4 v;
            __builtin_memcpy(&v, fb + (size_t)pi * CC + (col - 3), 16);
            vv[it] = v;
        } else {
            f32x4 v;
            #pragma unroll
            for (int j = 0; j < 4; ++j) {
                const int gg    = col + j;
                const int cross = (gg >= OUT_ROW) ? 1 : 0;
                const int rl2   = rl + cross;
                const int c2    = gg - cross * OUT_ROW;
                const int pi2   = s_pi[rl2];
                v[j] = (c2 < 3) ? pb[pi2 * 3 + c2]
                                : fb[(size_t)pi2 * CC + (c2 - 3)];
            }
            vv[it] = v;
        }
    }
    // phase 2: stream out (aligned NT dwordx4)
    #pragma unroll
    for (int it = 0; it < 5; ++it) {
        const int e4 = tid + it * 256;
        if (it == 4 && tid >= QPB - 1024) continue;
        __builtin_nontemporal_store(vv[it], oq + e4);
    }
}

extern "C" void kernel_launch(void* const* d_in, const int* in_sizes, int n_in,
                              void* d_out, int out_size, void* d_ws, size_t ws_size,
                              hipStream_t stream) {
    const float* points = (const float*)d_in[0];
    const float* feats  = (const float*)d_in[1];
    const float* boxes  = (const float*)d_in[2];
    float* out_feat = (float*)d_out;
    float* out_flag = (float*)d_out + (size_t)BB * MM * SS * OUT_ROW;

    int* ws_idx = (int*)d_ws;                       // 512*512 ints = 1 MB
    int* ws_cnt = ws_idx + (size_t)BB * MM * SS;    // 512 ints

    k1_select<<<BB * MM, 512, 0, stream>>>(points, boxes, ws_idx, ws_cnt, out_flag);
    k2_gather<<<BB * MM * G2, 256, 0, stream>>>(points, feats, ws_idx, ws_cnt, out_feat);
}